// Round 2
// baseline (10268.729 us; speedup 1.0000x reference)
//
#include <hip/hip_runtime.h>
#include <hip/hip_bf16.h>
#include <math.h>

// Problem dims (fixed)
#define T_STEPS 512
#define IN_DIM  1024
#define H_DIM   2048
#define Y_DIM   1024
#define NBLK    256      // blocks in sequential kernel (1 per CU nominal)
#define BTHREADS 512     // 8 waves; wave w owns output column jb+w

// ---------- helpers ----------
static __device__ __forceinline__ unsigned short f2bf(float f) {
    unsigned u = __float_as_uint(f);
    unsigned r = (u + 0x7FFFu + ((u >> 16) & 1u)) >> 16;   // RNE
    return (unsigned short)r;
}

// ---------- K1 / K3: tiled fp32 GEMM, C[M,N] = A[M,K] @ B[K,N] + bias[N] ----------
#define TM 64
#define TN 64
#define TK 16

__global__ __launch_bounds__(256) void gemm_bias(
    const float* __restrict__ A, const float* __restrict__ B,
    const float* __restrict__ bias, float* __restrict__ C,
    int M, int N, int K, int lda, int ldb, int ldc)
{
    __shared__ float As[TK][TM + 4];   // row stride 68 floats (16B aligned)
    __shared__ float Bs[TK][TN + 4];

    const int n0 = blockIdx.x * TN;
    const int m0 = blockIdx.y * TM;
    const int tid = threadIdx.x;
    const int tx = tid & 15;       // N direction, 4 cols each
    const int ty = tid >> 4;       // M direction, 4 rows each

    float acc[4][4] = {};

    for (int k0 = 0; k0 < K; k0 += TK) {
        // A tile 64x16 -> As[kk][tt]
        #pragma unroll
        for (int l = tid; l < TM * TK; l += 256) {
            int tt = l >> 4, kk = l & 15;
            As[kk][tt] = A[(m0 + tt) * lda + (k0 + kk)];
        }
        // B tile 16x64 -> Bs[kk][jj]
        #pragma unroll
        for (int l = tid; l < TK * TN; l += 256) {
            int kk = l >> 6, jj = l & 63;
            Bs[kk][jj] = B[(k0 + kk) * ldb + (n0 + jj)];
        }
        __syncthreads();
        #pragma unroll
        for (int kk = 0; kk < TK; ++kk) {
            float4 a = *(const float4*)&As[kk][ty * 4];
            float4 b = *(const float4*)&Bs[kk][tx * 4];
            acc[0][0] = fmaf(a.x, b.x, acc[0][0]);
            acc[0][1] = fmaf(a.x, b.y, acc[0][1]);
            acc[0][2] = fmaf(a.x, b.z, acc[0][2]);
            acc[0][3] = fmaf(a.x, b.w, acc[0][3]);
            acc[1][0] = fmaf(a.y, b.x, acc[1][0]);
            acc[1][1] = fmaf(a.y, b.y, acc[1][1]);
            acc[1][2] = fmaf(a.y, b.z, acc[1][2]);
            acc[1][3] = fmaf(a.y, b.w, acc[1][3]);
            acc[2][0] = fmaf(a.z, b.x, acc[2][0]);
            acc[2][1] = fmaf(a.z, b.y, acc[2][1]);
            acc[2][2] = fmaf(a.z, b.z, acc[2][2]);
            acc[2][3] = fmaf(a.z, b.w, acc[2][3]);
            acc[3][0] = fmaf(a.w, b.x, acc[3][0]);
            acc[3][1] = fmaf(a.w, b.y, acc[3][1]);
            acc[3][2] = fmaf(a.w, b.z, acc[3][2]);
            acc[3][3] = fmaf(a.w, b.w, acc[3][3]);
        }
        __syncthreads();
    }

    float4 bv = *(const float4*)&bias[n0 + tx * 4];
    #pragma unroll
    for (int r = 0; r < 4; ++r) {
        float4 o;
        o.x = acc[r][0] + bv.x;
        o.y = acc[r][1] + bv.y;
        o.z = acc[r][2] + bv.z;
        o.w = acc[r][3] + bv.w;
        *(float4*)&C[(m0 + ty * 4 + r) * ldc + (n0 + tx * 4)] = o;
    }
}

// ---------- K2: persistent sequential recurrence ----------
// Each block owns 8 h-columns (jb..jb+7). Recurrent weights (h-part of Wu/Wc,
// 2 x 2048 x 8 columns) live in LDS as packed bf16 pairs: 64 KiB, staged once.
// Per step: wave w computes both dot(h_prev, Wu_h[:,jb+w]) and dot(., Wc_h[:,jb+w]),
// lane0 applies gates and writes H[t][j]. Then a device-wide barrier.
__global__ __launch_bounds__(BTHREADS) void gru_seq(
    const float* __restrict__ Wu_h,   // = Wu + IN_DIM*H_DIM  (h-part rows)
    const float* __restrict__ Wc_h,
    const float* __restrict__ XU,     // [T,H]  x@Wu_x + bu
    const float* __restrict__ XC,     // [T,H]  x@Wc_x + bc
    const float* __restrict__ h0,     // [H]
    float* __restrict__ H,            // [T,H]
    unsigned* __restrict__ bar)
{
    __shared__ unsigned w_lds[2][8][H_DIM / 2];   // packed bf16 pairs, 64 KiB

    const int tid = threadIdx.x;
    const int jb = blockIdx.x * 8;

    // one-time weight staging: global fp32 (strided) -> LDS bf16 pairs
    for (int idx = tid; idx < 2 * 8 * (H_DIM / 2); idx += BTHREADS) {
        int m = idx >> 13;            // 0 = Wu, 1 = Wc
        int r = idx & 8191;
        int w = r >> 10;              // column within block
        int p = r & 1023;             // pair index (k = 2p, 2p+1)
        const float* W = m ? Wc_h : Wu_h;
        int j = jb + w;
        float v0 = W[(2 * p) * H_DIM + j];
        float v1 = W[(2 * p + 1) * H_DIM + j];
        w_lds[m][w][p] = (unsigned)f2bf(v0) | ((unsigned)f2bf(v1) << 16);
    }
    __syncthreads();

    const int w = tid >> 6;
    const int lane = tid & 63;
    const int j = jb + w;
    const unsigned* __restrict__ wu = w_lds[0][w];
    const unsigned* __restrict__ wc = w_lds[1][w];

    for (int t = 0; t < T_STEPS; ++t) {
        const float* __restrict__ hprev = t ? (H + (t - 1) * H_DIM) : h0;

        float au = 0.f, ac = 0.f;
        #pragma unroll
        for (int i = 0; i < 16; ++i) {
            int p = i * 64 + lane;
            float2 h2 = *(const float2*)(hprev + 2 * p);
            unsigned pu = wu[p];
            unsigned pc = wc[p];
            float u0 = __uint_as_float(pu << 16);
            float u1 = __uint_as_float(pu & 0xFFFF0000u);
            float c0 = __uint_as_float(pc << 16);
            float c1 = __uint_as_float(pc & 0xFFFF0000u);
            au = fmaf(h2.x, u0, au);
            au = fmaf(h2.y, u1, au);
            ac = fmaf(h2.x, c0, ac);
            ac = fmaf(h2.y, c1, ac);
        }
        // wave-level reduction (64 lanes)
        #pragma unroll
        for (int off = 32; off; off >>= 1) {
            au += __shfl_down(au, off);
            ac += __shfl_down(ac, off);
        }
        if (lane == 0) {
            float pre_u = au + XU[t * H_DIM + j];
            float pre_c = ac + XC[t * H_DIM + j];
            float ug = 1.f / (1.f + expf(-pre_u));
            float cg = tanhf(pre_c);
            float hp = hprev[j];
            H[t * H_DIM + j] = ug * cg + (1.f - ug) * hp;
        }

        // ---- device-wide barrier (monotonic counter, sense-free) ----
        __syncthreads();                       // drains this block's vmem (compiler emits vmcnt(0))
        if (tid == 0) {
            __threadfence();                   // release: write-back L2 so other XCDs see H[t]
            atomicAdd(bar, 1u);
            unsigned target = (unsigned)(t + 1) * NBLK;
            while (__hip_atomic_load(bar, __ATOMIC_RELAXED, __HIP_MEMORY_SCOPE_AGENT) < target) {
                __builtin_amdgcn_s_sleep(4);
            }
            __threadfence();                   // acquire: invalidate stale L1/L2 lines
        }
        __syncthreads();
    }
}

extern "C" void kernel_launch(void* const* d_in, const int* in_sizes, int n_in,
                              void* d_out, int out_size, void* d_ws, size_t ws_size,
                              hipStream_t stream)
{
    const float* x   = (const float*)d_in[0];   // [1,512,1024]
    const float* h0  = (const float*)d_in[1];   // [2048]
    const float* Wc  = (const float*)d_in[2];   // [3072,2048]
    const float* Wu  = (const float*)d_in[3];   // [3072,2048]
    const float* bc  = (const float*)d_in[4];   // [2048]
    const float* bu  = (const float*)d_in[5];   // [2048]
    const float* Why = (const float*)d_in[6];   // [2048,1024]
    const float* by  = (const float*)d_in[7];   // [1024]
    float* out = (float*)d_out;                 // ys[512*1024] then h_final[2048]

    float* ws = (float*)d_ws;
    float* XU = ws;                              // 512*2048 floats
    float* XC = ws + (T_STEPS * H_DIM);          // 512*2048
    float* H  = ws + 2 * (T_STEPS * H_DIM);      // 512*2048
    unsigned* bar = (unsigned*)(ws + 3 * (T_STEPS * H_DIM));

    hipMemsetAsync(bar, 0, 256, stream);

    // K1: XU = x @ Wu[0:1024,:] + bu ; XC = x @ Wc[0:1024,:] + bc
    gemm_bias<<<dim3(H_DIM / TN, T_STEPS / TM), 256, 0, stream>>>(
        x, Wu, bu, XU, T_STEPS, H_DIM, IN_DIM, IN_DIM, H_DIM, H_DIM);
    gemm_bias<<<dim3(H_DIM / TN, T_STEPS / TM), 256, 0, stream>>>(
        x, Wc, bc, XC, T_STEPS, H_DIM, IN_DIM, IN_DIM, H_DIM, H_DIM);

    // K2: sequential recurrence, persistent grid
    gru_seq<<<NBLK, BTHREADS, 0, stream>>>(
        Wu + IN_DIM * H_DIM, Wc + IN_DIM * H_DIM, XU, XC, h0, H, bar);

    // K3: ys = H @ Why + by
    gemm_bias<<<dim3(Y_DIM / TN, T_STEPS / TM), 256, 0, stream>>>(
        H, Why, by, out, T_STEPS, Y_DIM, H_DIM, H_DIM, Y_DIM, Y_DIM);

    // h_final = H[511]
    hipMemcpyAsync(out + T_STEPS * Y_DIM, H + (T_STEPS - 1) * H_DIM,
                   H_DIM * sizeof(float), hipMemcpyDeviceToDevice, stream);
}

// Round 3
// 2740.514 us; speedup vs baseline: 3.7470x; 3.7470x over previous
//
#include <hip/hip_runtime.h>
#include <hip/hip_bf16.h>
#include <math.h>

// Problem dims (fixed)
#define T_STEPS 512
#define IN_DIM  1024
#define H_DIM   2048
#define Y_DIM   1024
#define NBLK    256      // blocks in sequential kernel (1 per CU nominal)
#define BTHREADS 512     // 8 waves; wave w owns output column jb+w
#define NGRP    8        // two-level barrier: 8 group counters + 1 root
#define GRP_SZ  (NBLK / NGRP)   // 32 blocks per group

// ---------- helpers ----------
static __device__ __forceinline__ unsigned short f2bf(float f) {
    unsigned u = __float_as_uint(f);
    unsigned r = (u + 0x7FFFu + ((u >> 16) & 1u)) >> 16;   // RNE
    return (unsigned short)r;
}

// ---------- K1 / K3: tiled fp32 GEMM, C[M,N] = A[M,K] @ B[K,N] + bias[N] ----------
#define TM 64
#define TN 64
#define TK 16

__global__ __launch_bounds__(256) void gemm_bias(
    const float* __restrict__ A, const float* __restrict__ B,
    const float* __restrict__ bias, float* __restrict__ C,
    int M, int N, int K, int lda, int ldb, int ldc)
{
    __shared__ float As[TK][TM + 4];
    __shared__ float Bs[TK][TN + 4];

    const int n0 = blockIdx.x * TN;
    const int m0 = blockIdx.y * TM;
    const int tid = threadIdx.x;
    const int tx = tid & 15;       // N direction, 4 cols each
    const int ty = tid >> 4;       // M direction, 4 rows each

    float acc[4][4] = {};

    for (int k0 = 0; k0 < K; k0 += TK) {
        #pragma unroll
        for (int l = tid; l < TM * TK; l += 256) {
            int tt = l >> 4, kk = l & 15;
            As[kk][tt] = A[(m0 + tt) * lda + (k0 + kk)];
        }
        #pragma unroll
        for (int l = tid; l < TK * TN; l += 256) {
            int kk = l >> 6, jj = l & 63;
            Bs[kk][jj] = B[(k0 + kk) * ldb + (n0 + jj)];
        }
        __syncthreads();
        #pragma unroll
        for (int kk = 0; kk < TK; ++kk) {
            float4 a = *(const float4*)&As[kk][ty * 4];
            float4 b = *(const float4*)&Bs[kk][tx * 4];
            acc[0][0] = fmaf(a.x, b.x, acc[0][0]);
            acc[0][1] = fmaf(a.x, b.y, acc[0][1]);
            acc[0][2] = fmaf(a.x, b.z, acc[0][2]);
            acc[0][3] = fmaf(a.x, b.w, acc[0][3]);
            acc[1][0] = fmaf(a.y, b.x, acc[1][0]);
            acc[1][1] = fmaf(a.y, b.y, acc[1][1]);
            acc[1][2] = fmaf(a.y, b.z, acc[1][2]);
            acc[1][3] = fmaf(a.y, b.w, acc[1][3]);
            acc[2][0] = fmaf(a.z, b.x, acc[2][0]);
            acc[2][1] = fmaf(a.z, b.y, acc[2][1]);
            acc[2][2] = fmaf(a.z, b.z, acc[2][2]);
            acc[2][3] = fmaf(a.z, b.w, acc[2][3]);
            acc[3][0] = fmaf(a.w, b.x, acc[3][0]);
            acc[3][1] = fmaf(a.w, b.y, acc[3][1]);
            acc[3][2] = fmaf(a.w, b.z, acc[3][2]);
            acc[3][3] = fmaf(a.w, b.w, acc[3][3]);
        }
        __syncthreads();
    }

    float4 bv = *(const float4*)&bias[n0 + tx * 4];
    #pragma unroll
    for (int r = 0; r < 4; ++r) {
        float4 o;
        o.x = acc[r][0] + bv.x;
        o.y = acc[r][1] + bv.y;
        o.z = acc[r][2] + bv.z;
        o.w = acc[r][3] + bv.w;
        *(float4*)&C[(m0 + ty * 4 + r) * ldc + (n0 + tx * 4)] = o;
    }
}

// ---------- K2: persistent sequential recurrence, fence-free sc1 dataflow ----------
// All cross-block data (H rows, barrier counters) moves ONLY via agent-scope
// relaxed atomics (sc0/sc1: bypass L1/L2, hit the shared coherence point).
// No __threadfence => no buffer_wbl2/buffer_inv per step (was ~15us/step).
// Ordering: sc1 stores + s_waitcnt vmcnt(0) + s_barrier before the signal add.
__global__ __launch_bounds__(BTHREADS) void gru_seq(
    const float* __restrict__ Wu_h,   // = Wu + IN_DIM*H_DIM  (h-part rows)
    const float* __restrict__ Wc_h,
    const float* __restrict__ XU,     // [T,H]  x@Wu_x + bu
    const float* __restrict__ XC,     // [T,H]  x@Wc_x + bc
    const float* __restrict__ h0,     // [H]
    float* __restrict__ H,            // [T,H]
    unsigned* __restrict__ bar)       // [g*64]=group g (g<8), [512]=root
{
    __shared__ unsigned w_lds[2][8][H_DIM / 2];   // packed bf16 pairs, 64 KiB

    const int tid = threadIdx.x;
    const int jb = blockIdx.x * 8;

    // one-time weight staging: global fp32 (strided) -> LDS bf16 pairs
    for (int idx = tid; idx < 2 * 8 * (H_DIM / 2); idx += BTHREADS) {
        int m = idx >> 13;            // 0 = Wu, 1 = Wc
        int r = idx & 8191;
        int w = r >> 10;              // column within block
        int p = r & 1023;             // pair index (k = 2p, 2p+1)
        const float* W = m ? Wc_h : Wu_h;
        int j = jb + w;
        float v0 = W[(2 * p) * H_DIM + j];
        float v1 = W[(2 * p + 1) * H_DIM + j];
        w_lds[m][w][p] = (unsigned)f2bf(v0) | ((unsigned)f2bf(v1) << 16);
    }
    __syncthreads();

    const int w = tid >> 6;
    const int lane = tid & 63;
    const int j = jb + w;
    const unsigned* __restrict__ wu = w_lds[0][w];
    const unsigned* __restrict__ wc = w_lds[1][w];

    unsigned* grp  = bar + (blockIdx.x & (NGRP - 1)) * 64;   // 256B-spaced lines
    unsigned* root = bar + 512;

    for (int t = 0; t < T_STEPS; ++t) {
        // prefetch x-contributions for THIS step (read-only, normal cached loads;
        // latency hides under the barrier spin)
        float xu = 0.f, xc = 0.f;
        if (lane == 0) {
            xu = XU[t * H_DIM + j];
            xc = XC[t * H_DIM + j];
        }

        // ---- wait for step t-1 (all 256 blocks) ----
        if (t > 0 && tid == 0) {
            unsigned tgt = (unsigned)t * NGRP;
            while (__hip_atomic_load(root, __ATOMIC_RELAXED, __HIP_MEMORY_SCOPE_AGENT) < tgt) {
                __builtin_amdgcn_s_sleep(8);
            }
        }
        __syncthreads();

        const float* hsrc = t ? (H + (t - 1) * H_DIM) : h0;
        const unsigned long long* h64 = (const unsigned long long*)hsrc;

        float hp = 0.f;
        if (lane == 0) {
            hp = __hip_atomic_load((const float*)hsrc + j,
                                   __ATOMIC_RELAXED, __HIP_MEMORY_SCOPE_AGENT);
        }

        float au = 0.f, ac = 0.f;
        #pragma unroll
        for (int i = 0; i < 16; ++i) {
            int p = i * 64 + lane;
            unsigned long long v = __hip_atomic_load(h64 + p,
                                       __ATOMIC_RELAXED, __HIP_MEMORY_SCOPE_AGENT);
            float hx = __uint_as_float((unsigned)v);
            float hy = __uint_as_float((unsigned)(v >> 32));
            unsigned pu = wu[p];
            unsigned pc = wc[p];
            float u0 = __uint_as_float(pu << 16);
            float u1 = __uint_as_float(pu & 0xFFFF0000u);
            float c0 = __uint_as_float(pc << 16);
            float c1 = __uint_as_float(pc & 0xFFFF0000u);
            au = fmaf(hx, u0, au);
            au = fmaf(hy, u1, au);
            ac = fmaf(hx, c0, ac);
            ac = fmaf(hy, c1, ac);
        }
        // wave-level reduction (64 lanes)
        #pragma unroll
        for (int off = 32; off; off >>= 1) {
            au += __shfl_down(au, off);
            ac += __shfl_down(ac, off);
        }
        if (lane == 0) {
            float pre_u = au + xu;
            float pre_c = ac + xc;
            float ug = 1.f / (1.f + expf(-pre_u));
            float cg = tanhf(pre_c);
            float hnew = ug * cg + (1.f - ug) * hp;
            __hip_atomic_store(H + t * H_DIM + j, hnew,
                               __ATOMIC_RELAXED, __HIP_MEMORY_SCOPE_AGENT);
        }

        // drain this wave's sc1 store to the coherence point, then block-sync,
        // then signal. sc1 stores never linger in L2 => no wbL2 needed.
        asm volatile("s_waitcnt vmcnt(0)" ::: "memory");
        __syncthreads();
        if (tid == 0 && t < T_STEPS - 1) {
            unsigned old = __hip_atomic_fetch_add(grp, 1u,
                               __ATOMIC_RELAXED, __HIP_MEMORY_SCOPE_AGENT);
            if (old == (unsigned)(t + 1) * GRP_SZ - 1u) {
                __hip_atomic_fetch_add(root, 1u,
                                       __ATOMIC_RELAXED, __HIP_MEMORY_SCOPE_AGENT);
            }
        }
    }
}

extern "C" void kernel_launch(void* const* d_in, const int* in_sizes, int n_in,
                              void* d_out, int out_size, void* d_ws, size_t ws_size,
                              hipStream_t stream)
{
    const float* x   = (const float*)d_in[0];   // [1,512,1024]
    const float* h0  = (const float*)d_in[1];   // [2048]
    const float* Wc  = (const float*)d_in[2];   // [3072,2048]
    const float* Wu  = (const float*)d_in[3];   // [3072,2048]
    const float* bc  = (const float*)d_in[4];   // [2048]
    const float* bu  = (const float*)d_in[5];   // [2048]
    const float* Why = (const float*)d_in[6];   // [2048,1024]
    const float* by  = (const float*)d_in[7];   // [1024]
    float* out = (float*)d_out;                 // ys[512*1024] then h_final[2048]

    float* ws = (float*)d_ws;
    float* XU = ws;                              // 512*2048 floats
    float* XC = ws + (T_STEPS * H_DIM);          // 512*2048
    float* H  = ws + 2 * (T_STEPS * H_DIM);      // 512*2048
    unsigned* bar = (unsigned*)(ws + 3 * (T_STEPS * H_DIM));

    hipMemsetAsync(bar, 0, 4096, stream);

    // K1: XU = x @ Wu[0:1024,:] + bu ; XC = x @ Wc[0:1024,:] + bc
    gemm_bias<<<dim3(H_DIM / TN, T_STEPS / TM), 256, 0, stream>>>(
        x, Wu, bu, XU, T_STEPS, H_DIM, IN_DIM, IN_DIM, H_DIM, H_DIM);
    gemm_bias<<<dim3(H_DIM / TN, T_STEPS / TM), 256, 0, stream>>>(
        x, Wc, bc, XC, T_STEPS, H_DIM, IN_DIM, IN_DIM, H_DIM, H_DIM);

    // K2: sequential recurrence, persistent grid, fence-free sc1 dataflow
    gru_seq<<<NBLK, BTHREADS, 0, stream>>>(
        Wu + IN_DIM * H_DIM, Wc + IN_DIM * H_DIM, XU, XC, h0, H, bar);

    // K3: ys = H @ Why + by
    gemm_bias<<<dim3(Y_DIM / TN, T_STEPS / TM), 256, 0, stream>>>(
        H, Why, by, out, T_STEPS, Y_DIM, H_DIM, H_DIM, Y_DIM, Y_DIM);

    // h_final = H[511]
    hipMemcpyAsync(out + T_STEPS * Y_DIM, H + (T_STEPS - 1) * H_DIM,
                   H_DIM * sizeof(float), hipMemcpyDeviceToDevice, stream);
}